// Round 2
// 295.028 us; speedup vs baseline: 1.0413x; 1.0413x over previous
//
#include <hip/hip_runtime.h>

// Walsh-Hadamard, N = 2^25 fp32. Two passes (stages commute):
//   pass1: bits 0..13 within contiguous 2^14 tiles (+ nt loads)
//   pass2: bits 14..24 = column transform of a (2048 x 2^14) matrix view
// pass2: 512 thr x 32 float4, 128 KiB LDS, all-lane half-round
// exchanges (6 barriers, bank-conflict-free), 128-B coalesced nt stores.

// clang's nontemporal builtins reject HIP_vector_type -> go through a
// native ext_vector_type alias (bit-identical layout).
typedef float vf4 __attribute__((ext_vector_type(4)));

__device__ __forceinline__ float4 ntload(const float4* p) {
  vf4 r = __builtin_nontemporal_load(reinterpret_cast<const vf4*>(p));
  return *reinterpret_cast<float4*>(&r);
}
__device__ __forceinline__ void ntstore(float4* p, float4 v) {
  __builtin_nontemporal_store(*reinterpret_cast<vf4*>(&v),
                              reinterpret_cast<vf4*>(p));
}

__device__ __forceinline__ void bfly(float4& a, float4& b) {
  float ax = a.x, ay = a.y, az = a.z, aw = a.w;
  a.x = ax + b.x; a.y = ay + b.y; a.z = az + b.z; a.w = aw + b.w;
  b.x = ax - b.x; b.y = ay - b.y; b.z = az - b.z; b.w = aw - b.w;
}

// 4 butterfly stages across the 4 index bits of v[16]
__device__ __forceinline__ void cross4(float4 (&v)[16]) {
#pragma unroll
  for (int m = 0; m < 4; ++m) {
#pragma unroll
    for (int k = 0; k < 16; ++k) {
      if (!(k & (1 << m))) bfly(v[k], v[k | (1 << m)]);
    }
  }
}

// ---------------- pass 1: bits 0..13 ----------------
// tile = 2^14 floats, 256 threads, 16 float4/thread, 64 KiB LDS.
// LDS float4-index swizzle: L(q) = q ^ ((q>>4)&15) -> conflict-free.
// Loads are nontemporal: x is read exactly once; keep L3 for the
// intermediate (written by pass1, read by pass2).
__global__ __launch_bounds__(256) void wht_pass1(const float4* __restrict__ in4,
                                                 float4* __restrict__ out4) {
  __shared__ float4 lds[4096];  // 64 KiB
  const int t = threadIdx.x;
  const int base4 = (int)blockIdx.x << 12;  // tile base in float4s
  float4 v[16];
#pragma unroll
  for (int k = 0; k < 16; ++k)
    v[k] = ntload(&in4[base4 + t + (k << 8)]);
  // bits 0 and 1 (inside each float4)
#pragma unroll
  for (int k = 0; k < 16; ++k) {
    float4 a = v[k];
    float s0 = a.x + a.y, d0 = a.x - a.y, s1 = a.z + a.w, d1 = a.z - a.w;
    v[k].x = s0 + s1; v[k].y = d0 + d1; v[k].z = s0 - s1; v[k].w = d0 - d1;
  }
  cross4(v);  // bits 10..13 (k = e[13:10])

  // exchange 1: -> thread holds u = e[5:2]
#pragma unroll
  for (int k = 0; k < 16; ++k) { int q = t + (k << 8); lds[q ^ ((q >> 4) & 15)] = v[k]; }
  __syncthreads();
#pragma unroll
  for (int u = 0; u < 16; ++u) { int q = u + (t << 4); v[u] = lds[q ^ ((q >> 4) & 15)]; }
  cross4(v);  // bits 2..5

  // exchange 2: write set == own read set -> no barrier needed before writes
#pragma unroll
  for (int u = 0; u < 16; ++u) { int q = u + (t << 4); lds[q ^ ((q >> 4) & 15)] = v[u]; }
  __syncthreads();
  const int c0 = t & 15, c1 = t >> 4;
#pragma unroll
  for (int u = 0; u < 16; ++u) {
    int q = c0 + (u << 4) + (c1 << 8);
    v[u] = lds[q ^ ((q >> 4) & 15)];
  }
  cross4(v);  // bits 6..9 (u = e[9:6])

#pragma unroll
  for (int u = 0; u < 16; ++u) out4[base4 + c0 + (u << 4) + (c1 << 8)] = v[u];
}

// ---------------- pass 2: bits 14..24 ----------------
// Matrix view: 2048 rows (idx>>14) x 2^12 float4-cols. Block = 8 f4-cols x
// all rows = 256 KiB; 512 threads x 32 float4. LDS = 128 KiB (half the
// block data) -> each exchange runs as 2 all-lane half-rounds over r10.
// LDS slot = (row & 1023)*8 + c4: c4 (= t&7) is always the fastest lane
// bits -> every ds access pattern is bank-conflict-free (row stride 128 B).
// Bit schedule: cross5 on r6..r10 (regs k) | x1 -> cross4 on r0..r3 |
// x2 -> cross2 on r4..r5. r10 / r0,r1 ride as non-crossed reg bits.
__global__ __launch_bounds__(512) void wht_pass2(float4* __restrict__ b4) {
  __shared__ float4 lds[8192];  // 128 KiB
  const int t = threadIdx.x;
  const int cb4 = (int)blockIdx.x << 3;  // column base in float4s (32 cols)
  const int c4 = t & 7;                  // float4-col within block
  const int rlo = t >> 3;                // row bits 0..5 (load layout)
  float4 v[32];
#pragma unroll
  for (int k = 0; k < 32; ++k)
    v[k] = ntload(&b4[((rlo + (k << 6)) << 12) + cb4 + c4]);

  // cross row bits 6..10 (k bits 0..4)
#pragma unroll
  for (int m = 0; m < 5; ++m) {
#pragma unroll
    for (int k = 0; k < 32; ++k)
      if (!(k & (1 << m))) bfly(v[k], v[k | (1 << m)]);
  }

  const int rhi6 = t >> 3;  // row bits 4..9 (post-exchange-1 layout)

  // exchange 1: regs k = r[10:6]  ->  regs j = {r10, r[3:0]}
  // half-round b = r10. Writer slot key = row&1023 = rlo | k16<<6;
  // reader key = j16 | rhi6<<4. All lanes active in every phase.
#pragma unroll
  for (int b = 0; b < 2; ++b) {
    if (b) __syncthreads();  // W1 must wait for all R0
#pragma unroll
    for (int k16 = 0; k16 < 16; ++k16)
      lds[((rlo + (k16 << 6)) << 3) + c4] = v[(b << 4) | k16];
    __syncthreads();
#pragma unroll
    for (int j16 = 0; j16 < 16; ++j16)
      v[(b << 4) | j16] = lds[((j16 + (rhi6 << 4)) << 3) + c4];
  }
  // cross row bits 0..3 (j bits 0..3; bit 4 = r10 rides)
  cross4(*reinterpret_cast<float4(*)[16]>(&v[0]));
  cross4(*reinterpret_cast<float4(*)[16]>(&v[16]));

  // exchange 2: regs j = {r10, r[3:0]} -> regs i' = {r10, r1, r0, r5, r4}
  // W0' targets this thread's own exchange-1 read-slot set -> no barrier
  // needed between R1 and W0'.
#pragma unroll
  for (int b = 0; b < 2; ++b) {
    if (b) __syncthreads();  // W1' must wait for all R0'
#pragma unroll
    for (int j16 = 0; j16 < 16; ++j16)
      lds[((j16 + (rhi6 << 4)) << 3) + c4] = v[(b << 4) | j16];
    __syncthreads();
#pragma unroll
    for (int i = 0; i < 16; ++i) {
      // i bits 0..1 = r4,r5 (to cross); i bits 2..3 = r0,r1 (ride).
      // thread: t[4:3] = r3,r2 ; t[8:5] = r9..r6.
      int rowkey = ((i >> 2) & 3) | (((t >> 3) & 3) << 2) | ((i & 3) << 4) |
                   ((t >> 5) << 6);
      v[(b << 4) | i] = lds[(rowkey << 3) + c4];
    }
  }
  // cross row bits 4..5 (i bits 0..1)
#pragma unroll
  for (int m = 0; m < 2; ++m) {
#pragma unroll
    for (int i = 0; i < 32; ++i)
      if (!(i & (1 << m))) bfly(v[i], v[i | (1 << m)]);
  }

  // store: row = rowkey | (b<<10); per instruction a wave writes 8 rows x
  // 128 B contiguous. Nontemporal: never re-read on GPU.
#pragma unroll
  for (int i2 = 0; i2 < 32; ++i2) {
    int b = i2 >> 4, i = i2 & 15;
    int rowkey = ((i >> 2) & 3) | (((t >> 3) & 3) << 2) | ((i & 3) << 4) |
                 ((t >> 5) << 6);
    int row = rowkey | (b << 10);
    ntstore(&b4[(row << 12) + cb4 + c4], v[i2]);
  }
}

extern "C" void kernel_launch(void* const* d_in, const int* in_sizes, int n_in,
                              void* d_out, int out_size, void* d_ws, size_t ws_size,
                              hipStream_t stream) {
  (void)in_sizes; (void)n_in; (void)d_ws; (void)ws_size; (void)out_size;
  const float* x = (const float*)d_in[0];
  float* out = (float*)d_out;
  // pass1: 2^25 / 2^14 = 2048 tiles
  wht_pass1<<<2048, 256, 0, stream>>>((const float4*)x, (float4*)out);
  // pass2: 2^12 f4-cols / 8 = 512 tiles, in-place on d_out
  wht_pass2<<<512, 512, 0, stream>>>((float4*)out);
}